// Round 1
// baseline (193.069 us; speedup 1.0000x reference)
//
#include <hip/hip_runtime.h>
#include <math.h>

#define W_ 4
#define S_ 32
#define H_ 32
#define KH_ 8
#define D_ 128
#define BS_ 16
#define M_ 64
#define NB_ 2048
#define G_ (H_ / KH_)  // 4
#define SCALE_ 0.08838834764831845f

// Phase 1: per-(rank, seq, kv-head) paged attention. 256 threads = 4 waves,
// wave g handles query head kh*G_+g independently (no barriers in main loop).
// KV page slice layout is [D][BS] (t contiguous) -> all global reads are
// coalesced float4 wave reads. No LDS in the main loop.
__global__ __launch_bounds__(256) void pa_phase1(
    const float* __restrict__ q, const float* __restrict__ kc,
    const float* __restrict__ vc, const int* __restrict__ bt,
    const int* __restrict__ cl, float* __restrict__ o_ws,
    float* __restrict__ m_ws, float* __restrict__ se_ws) {
  const int wg = blockIdx.x;
  const int kh = wg & (KH_ - 1);
  const int s = (wg / KH_) & (S_ - 1);
  const int w = wg / (KH_ * S_);
  const int lane = threadIdx.x & 63;
  const int g = threadIdx.x >> 6;
  const int d_sub = lane >> 2;  // 0..15
  const int tc = lane & 3;      // 0..3 : lane owns tokens t = 4*tc..4*tc+3 of each page

  const int ctx = cl[w * S_ + s];
  const int nblk = (ctx + BS_ - 1) >> 4;
  const int* bt_row = bt + (w * S_ + s) * M_;

  // q fragment: q[h][d_sub + 16*i], i = 0..7 (matches K read pattern below)
  const float* qrow = q + ((size_t)(s * H_) + kh * G_ + g) * D_;
  float qreg[8];
#pragma unroll
  for (int i = 0; i < 8; ++i) qreg[i] = qrow[d_sub + 16 * i];

  float oacc0 = 0.f, oacc1 = 0.f;   // lane owns output dims d=lane and d=lane+64
  float m_run = -INFINITY, se_run = 0.f;

  for (int j = 0; j < nblk; ++j) {
    const int page = bt_row[j];
    const size_t pbase = ((((size_t)w * NB_ + page) * KH_) + kh) * (size_t)(D_ * BS_);
    const float* Kc = kc + pbase;
    const float* Vc = vc + pbase;

    // ---- QK^T: acc4[c] = sum_d q[d] * K[d][4*tc+c], lane covers d = d_sub+16i
    float4 a4 = make_float4(0.f, 0.f, 0.f, 0.f);
#pragma unroll
    for (int i = 0; i < 8; ++i) {
      const float4 k4 =
          *reinterpret_cast<const float4*>(Kc + (d_sub + 16 * i) * BS_ + 4 * tc);
      a4.x = fmaf(qreg[i], k4.x, a4.x);
      a4.y = fmaf(qreg[i], k4.y, a4.y);
      a4.z = fmaf(qreg[i], k4.z, a4.z);
      a4.w = fmaf(qreg[i], k4.w, a4.w);
    }
    // reduce over the 16 d_sub values (lane bits 2..5); tc classes stay intact
#pragma unroll
    for (int off = 4; off <= 32; off <<= 1) {
      a4.x += __shfl_xor(a4.x, off);
      a4.y += __shfl_xor(a4.y, off);
      a4.z += __shfl_xor(a4.z, off);
      a4.w += __shfl_xor(a4.w, off);
    }

    const int tbase = j * BS_ + 4 * tc;
    const float l0 = (tbase + 0 < ctx) ? a4.x * SCALE_ : -INFINITY;
    const float l1 = (tbase + 1 < ctx) ? a4.y * SCALE_ : -INFINITY;
    const float l2 = (tbase + 2 < ctx) ? a4.z * SCALE_ : -INFINITY;
    const float l3 = (tbase + 3 < ctx) ? a4.w * SCALE_ : -INFINITY;

    float bm = fmaxf(fmaxf(l0, l1), fmaxf(l2, l3));
    bm = fmaxf(bm, __shfl_xor(bm, 1));
    bm = fmaxf(bm, __shfl_xor(bm, 2));  // max over all 16 tokens (all lanes)

    const float m_new = fmaxf(m_run, bm);     // first page: bm finite (ctx>=1)
    const float corr = __expf(m_run - m_new); // exp(-inf)=0 on first page
    const float p0 = __expf(l0 - m_new);
    const float p1 = __expf(l1 - m_new);
    const float p2 = __expf(l2 - m_new);
    const float p3 = __expf(l3 - m_new);
    float ps = p0 + p1 + p2 + p3;
    ps += __shfl_xor(ps, 1);
    ps += __shfl_xor(ps, 2);
    se_run = se_run * corr + ps;
    m_run = m_new;
    oacc0 *= corr;
    oacc1 *= corr;

    // ---- broadcast p[t] to all lanes (compile-time lanes -> v_readlane)
    float pb[16];
#pragma unroll
    for (int t = 0; t < 16; ++t) {
      const int c = t & 3;
      const float src = (c == 0) ? p0 : (c == 1) ? p1 : (c == 2) ? p2 : p3;
      pb[t] = __shfl(src, t >> 2);
    }

    // ---- PV: lane accumulates o[d=lane], o[d=lane+64]; V[d][t] rows contiguous
    float v0[16], v1[16];
    const float* V0 = Vc + lane * BS_;
    const float* V1 = Vc + (lane + 64) * BS_;
#pragma unroll
    for (int u = 0; u < 4; ++u) {
      *reinterpret_cast<float4*>(v0 + 4 * u) =
          *reinterpret_cast<const float4*>(V0 + 4 * u);
      *reinterpret_cast<float4*>(v1 + 4 * u) =
          *reinterpret_cast<const float4*>(V1 + 4 * u);
    }
#pragma unroll
    for (int t = 0; t < 16; ++t) {
      oacc0 = fmaf(pb[t], v0[t], oacc0);
      oacc1 = fmaf(pb[t], v1[t], oacc1);
    }
  }

  // store unnormalized O-hat, running max, exp-sum
  const size_t gidx = (((size_t)w * S_ + s) * KH_ + kh) * G_ + g;
  o_ws[gidx * D_ + lane] = oacc0;
  o_ws[gidx * D_ + lane + 64] = oacc1;
  if (lane == 0) {
    m_ws[gidx] = m_run;
    se_ws[gidx] = se_run;
  }
}

// Phase 2: merge per-rank softmax states across W ranks.
// out = sum_w exp(m_w - m_g) * Ohat_w / sum_w se_w * exp(m_w - m_g)
__global__ __launch_bounds__(128) void pa_reduce(
    const float* __restrict__ o_ws, const float* __restrict__ m_ws,
    const float* __restrict__ se_ws, float* __restrict__ out) {
  const int grp = blockIdx.x;  // ((s*KH + kh)*G + g)  == (s*H + h)
  const int d = threadIdx.x;   // 0..127
  const int NG = S_ * KH_ * G_;  // 1024

  float mw[W_];
  float mg = -INFINITY;
#pragma unroll
  for (int w = 0; w < W_; ++w) {
    mw[w] = m_ws[w * NG + grp];
    mg = fmaxf(mg, mw[w]);
  }
  float denom = 0.f, acc = 0.f;
#pragma unroll
  for (int w = 0; w < W_; ++w) {
    const float e = __expf(mw[w] - mg);
    denom = fmaf(se_ws[w * NG + grp], e, denom);
    acc = fmaf(e, o_ws[((size_t)w * NG + grp) * D_ + d], acc);
  }
  out[(size_t)grp * D_ + d] = acc / denom;
}

extern "C" void kernel_launch(void* const* d_in, const int* in_sizes, int n_in,
                              void* d_out, int out_size, void* d_ws, size_t ws_size,
                              hipStream_t stream) {
  (void)in_sizes; (void)n_in; (void)out_size; (void)ws_size;
  const float* q = (const float*)d_in[0];
  const float* kc = (const float*)d_in[1];
  const float* vc = (const float*)d_in[2];
  const int* bt = (const int*)d_in[3];
  const int* cl = (const int*)d_in[4];

  float* o_ws = (float*)d_ws;                                   // W*S*KH*G*D floats (2 MB)
  float* m_ws = o_ws + (size_t)W_ * S_ * KH_ * G_ * D_;         // W*S*KH*G floats
  float* se_ws = m_ws + (size_t)W_ * S_ * KH_ * G_;             // W*S*KH*G floats
  float* out = (float*)d_out;

  pa_phase1<<<dim3(W_ * S_ * KH_), dim3(256), 0, stream>>>(q, kc, vc, bt, cl,
                                                           o_ws, m_ws, se_ws);
  pa_reduce<<<dim3(S_ * KH_ * G_), dim3(128), 0, stream>>>(o_ws, m_ws, se_ws, out);
}

// Round 2
// 140.979 us; speedup vs baseline: 1.3695x; 1.3695x over previous
//
#include <hip/hip_runtime.h>
#include <math.h>

#define W_ 4
#define S_ 32
#define H_ 32
#define KH_ 8
#define D_ 128
#define BS_ 16
#define M_ 64
#define NB_ 2048
#define G_ (H_ / KH_)        // 4
#define NG_ (S_ * KH_ * G_)  // 1024 groups (== S*H)
#define SCALE_ 0.08838834764831845f

// Phase 1: flash-decode. Each block handles one (rank, seq, kv-head, split):
// a contiguous range of pages. 256 threads = 4 waves, wave g = query head
// kh*G_+g (independent, no barriers). KV page slice layout [D][BS] ->
// all global reads are coalesced float4 wave reads. No LDS.
template <int NSPLIT>
__global__ __launch_bounds__(256) void pa_phase1(
    const float* __restrict__ q, const float* __restrict__ kc,
    const float* __restrict__ vc, const int* __restrict__ bt,
    const int* __restrict__ cl, float* __restrict__ o_ws,
    float* __restrict__ m_ws, float* __restrict__ se_ws) {
  const int wg = blockIdx.x;
  const int split = wg % NSPLIT;
  const int kh = (wg / NSPLIT) % KH_;
  const int s = (wg / (NSPLIT * KH_)) % S_;
  const int w = wg / (NSPLIT * KH_ * S_);
  const int lane = threadIdx.x & 63;
  const int g = threadIdx.x >> 6;
  const int d_sub = lane >> 2;  // 0..15
  const int tc = lane & 3;      // lane owns tokens t = 4*tc..4*tc+3 of each page

  const int ctx = cl[w * S_ + s];
  const int nblk = (ctx + BS_ - 1) >> 4;
  const int pps = (nblk + NSPLIT - 1) / NSPLIT;  // pages per split
  const int j0 = split * pps;
  const int j1 = min(j0 + pps, nblk);
  const int* bt_row = bt + (w * S_ + s) * M_;

  const float* qrow = q + ((size_t)(s * H_) + kh * G_ + g) * D_;
  float qreg[8];
#pragma unroll
  for (int i = 0; i < 8; ++i) qreg[i] = qrow[d_sub + 16 * i];

  float oacc0 = 0.f, oacc1 = 0.f;  // lane owns output dims d=lane, d=lane+64
  float m_run = -INFINITY, se_run = 0.f;

  for (int j = j0; j < j1; ++j) {
    const int page = bt_row[j];
    const size_t pbase = ((((size_t)w * NB_ + page) * KH_) + kh) * (size_t)(D_ * BS_);
    const float* Kc = kc + pbase;
    const float* Vc = vc + pbase;

    // ---- QK^T: acc4[c] = sum_d q[d] * K[d][4*tc+c], lane covers d = d_sub+16i
    float4 a4 = make_float4(0.f, 0.f, 0.f, 0.f);
#pragma unroll
    for (int i = 0; i < 8; ++i) {
      const float4 k4 =
          *reinterpret_cast<const float4*>(Kc + (d_sub + 16 * i) * BS_ + 4 * tc);
      a4.x = fmaf(qreg[i], k4.x, a4.x);
      a4.y = fmaf(qreg[i], k4.y, a4.y);
      a4.z = fmaf(qreg[i], k4.z, a4.z);
      a4.w = fmaf(qreg[i], k4.w, a4.w);
    }
#pragma unroll
    for (int off = 4; off <= 32; off <<= 1) {
      a4.x += __shfl_xor(a4.x, off);
      a4.y += __shfl_xor(a4.y, off);
      a4.z += __shfl_xor(a4.z, off);
      a4.w += __shfl_xor(a4.w, off);
    }

    const int tbase = j * BS_ + 4 * tc;
    const float l0 = (tbase + 0 < ctx) ? a4.x * SCALE_ : -INFINITY;
    const float l1 = (tbase + 1 < ctx) ? a4.y * SCALE_ : -INFINITY;
    const float l2 = (tbase + 2 < ctx) ? a4.z * SCALE_ : -INFINITY;
    const float l3 = (tbase + 3 < ctx) ? a4.w * SCALE_ : -INFINITY;

    float bm = fmaxf(fmaxf(l0, l1), fmaxf(l2, l3));
    bm = fmaxf(bm, __shfl_xor(bm, 1));
    bm = fmaxf(bm, __shfl_xor(bm, 2));  // max over the page's 16 tokens

    const float m_new = fmaxf(m_run, bm);
    const float corr = __expf(m_run - m_new);
    const float p0 = __expf(l0 - m_new);
    const float p1 = __expf(l1 - m_new);
    const float p2 = __expf(l2 - m_new);
    const float p3 = __expf(l3 - m_new);
    float ps = p0 + p1 + p2 + p3;
    ps += __shfl_xor(ps, 1);
    ps += __shfl_xor(ps, 2);
    se_run = se_run * corr + ps;
    m_run = m_new;
    oacc0 *= corr;
    oacc1 *= corr;

    // broadcast p[t] to all lanes (compile-time lanes -> readlane)
    float pb[16];
#pragma unroll
    for (int t = 0; t < 16; ++t) {
      const int c = t & 3;
      const float src = (c == 0) ? p0 : (c == 1) ? p1 : (c == 2) ? p2 : p3;
      pb[t] = __shfl(src, t >> 2);
    }

    // ---- PV: V[d][t] rows contiguous; lane reads d=lane and d=lane+64
    float v0[16], v1[16];
    const float* V0 = Vc + lane * BS_;
    const float* V1 = Vc + (lane + 64) * BS_;
#pragma unroll
    for (int u = 0; u < 4; ++u) {
      *reinterpret_cast<float4*>(v0 + 4 * u) =
          *reinterpret_cast<const float4*>(V0 + 4 * u);
      *reinterpret_cast<float4*>(v1 + 4 * u) =
          *reinterpret_cast<const float4*>(V1 + 4 * u);
    }
#pragma unroll
    for (int t = 0; t < 16; ++t) {
      oacc0 = fmaf(pb[t], v0[t], oacc0);
      oacc1 = fmaf(pb[t], v1[t], oacc1);
    }
  }

  // store unnormalized O-hat, running max, exp-sum for partial r
  const int grp = (s * KH_ + kh) * G_ + g;      // == s*H + h
  const int r = w * NSPLIT + split;
  const size_t gidx = (size_t)r * NG_ + grp;
  o_ws[gidx * D_ + lane] = oacc0;
  o_ws[gidx * D_ + lane + 64] = oacc1;
  if (lane == 0) {
    m_ws[gidx] = m_run;   // -inf if this split had no pages
    se_ws[gidx] = se_run;
  }
}

// Phase 2: merge R = W*NSPLIT partial softmax states per group.
// out = sum_r exp(m_r - m_g) * Ohat_r / sum_r se_r * exp(m_r - m_g)
template <int R>
__global__ __launch_bounds__(128) void pa_reduce(
    const float* __restrict__ o_ws, const float* __restrict__ m_ws,
    const float* __restrict__ se_ws, float* __restrict__ out) {
  const int grp = blockIdx.x;  // s*H + h
  const int d = threadIdx.x;   // 0..127

  float mw[R];
  float mg = -INFINITY;
#pragma unroll
  for (int r = 0; r < R; ++r) {
    mw[r] = m_ws[(size_t)r * NG_ + grp];
    mg = fmaxf(mg, mw[r]);
  }
  float denom = 0.f, acc = 0.f;
#pragma unroll
  for (int r = 0; r < R; ++r) {
    const float e = __expf(mw[r] - mg);  // 0 for empty partials (m=-inf)
    denom = fmaf(se_ws[(size_t)r * NG_ + grp], e, denom);
    acc = fmaf(e, o_ws[((size_t)r * NG_ + grp) * D_ + d], acc);
  }
  out[(size_t)grp * D_ + d] = acc / denom;
}

extern "C" void kernel_launch(void* const* d_in, const int* in_sizes, int n_in,
                              void* d_out, int out_size, void* d_ws, size_t ws_size,
                              hipStream_t stream) {
  (void)in_sizes; (void)n_in; (void)out_size;
  const float* q = (const float*)d_in[0];
  const float* kc = (const float*)d_in[1];
  const float* vc = (const float*)d_in[2];
  const int* bt = (const int*)d_in[3];
  const int* cl = (const int*)d_in[4];
  float* out = (float*)d_out;

  // pick largest NSPLIT whose partial-state workspace fits ws_size
  int nsplit = 8;
  while (nsplit > 1 &&
         (size_t)(W_ * nsplit) * NG_ * (D_ + 2) * sizeof(float) > ws_size)
    nsplit >>= 1;

  float* o_ws = (float*)d_ws;                              // W*nsplit*NG*D floats
  float* m_ws = o_ws + (size_t)W_ * nsplit * NG_ * D_;     // W*nsplit*NG
  float* se_ws = m_ws + (size_t)W_ * nsplit * NG_;         // W*nsplit*NG

  const dim3 blk1(256), blk2(128);
  const dim3 grid2(NG_);
  switch (nsplit) {
    case 8:
      pa_phase1<8><<<dim3(W_ * S_ * KH_ * 8), blk1, 0, stream>>>(q, kc, vc, bt, cl, o_ws, m_ws, se_ws);
      pa_reduce<32><<<grid2, blk2, 0, stream>>>(o_ws, m_ws, se_ws, out);
      break;
    case 4:
      pa_phase1<4><<<dim3(W_ * S_ * KH_ * 4), blk1, 0, stream>>>(q, kc, vc, bt, cl, o_ws, m_ws, se_ws);
      pa_reduce<16><<<grid2, blk2, 0, stream>>>(o_ws, m_ws, se_ws, out);
      break;
    case 2:
      pa_phase1<2><<<dim3(W_ * S_ * KH_ * 2), blk1, 0, stream>>>(q, kc, vc, bt, cl, o_ws, m_ws, se_ws);
      pa_reduce<8><<<grid2, blk2, 0, stream>>>(o_ws, m_ws, se_ws, out);
      break;
    default:
      pa_phase1<1><<<dim3(W_ * S_ * KH_), blk1, 0, stream>>>(q, kc, vc, bt, cl, o_ws, m_ws, se_ws);
      pa_reduce<4><<<grid2, blk2, 0, stream>>>(o_ws, m_ws, se_ws, out);
      break;
  }
}